// Round 1
// baseline (396.067 us; speedup 1.0000x reference)
//
#include <hip/hip_runtime.h>
#include <hip/hip_bf16.h>
#include <cstdint>

typedef short v8s __attribute__((ext_vector_type(8)));
typedef float v4f __attribute__((ext_vector_type(4)));

#define DEV __device__ __forceinline__

DEV unsigned short f2bu(float f) {
  unsigned u = __builtin_bit_cast(unsigned, f);
  u += 0x7fffu + ((u >> 16) & 1u);   // RNE to bf16
  return (unsigned short)(u >> 16);
}

DEV v8s pack8(const float4& a, const float4& b) {
  v8s r;
  r[0] = (short)f2bu(a.x); r[1] = (short)f2bu(a.y);
  r[2] = (short)f2bu(a.z); r[3] = (short)f2bu(a.w);
  r[4] = (short)f2bu(b.x); r[5] = (short)f2bu(b.y);
  r[6] = (short)f2bu(b.z); r[7] = (short)f2bu(b.w);
  return r;
}

// ---------------- K1: deg -> dinv = rsqrt(1 + rowsum(A)) ----------------
__global__ __launch_bounds__(256)
void k_deg(const float* __restrict__ A, float* __restrict__ dinv) {
  const int row = blockIdx.x;
  const float* ar = A + (size_t)row * 8192;
  float s = 0.f;
  for (int base = 0; base < 8192; base += 1024) {
    float4 v = *(const float4*)(ar + base + threadIdx.x * 4);
    s += (v.x + v.y) + (v.z + v.w);
  }
  #pragma unroll
  for (int d = 1; d < 64; d <<= 1) s += __shfl_xor(s, d);
  __shared__ float wsum[4];
  if ((threadIdx.x & 63) == 0) wsum[threadIdx.x >> 6] = s;
  __syncthreads();
  if (threadIdx.x == 0) {
    float tot = 1.0f + ((wsum[0] + wsum[1]) + (wsum[2] + wsum[3]));
    dinv[row] = rsqrtf(tot);
  }
}

// -------- K2/K4: [8192][128] f32 -> [128][8192] bf16, optional row scale --------
template<bool SCALE>
__global__ __launch_bounds__(256)
void k_transpose(const float* __restrict__ in, unsigned short* __restrict__ out,
                 const float* __restrict__ dinv) {
  __shared__ float tile[64][129];
  const int j0 = blockIdx.x * 64;
  const int t = threadIdx.x;
  const int r0 = t >> 5, sl = t & 31;
  #pragma unroll
  for (int i = 0; i < 8; ++i) {
    int r = r0 + i * 8;
    float4 v = *(const float4*)(in + (size_t)(j0 + r) * 128 + sl * 4);
    float sc = 1.0f;
    if constexpr (SCALE) sc = dinv[j0 + r];
    tile[r][sl * 4 + 0] = v.x * sc;
    tile[r][sl * 4 + 1] = v.y * sc;
    tile[r][sl * 4 + 2] = v.z * sc;
    tile[r][sl * 4 + 3] = v.w * sc;
  }
  __syncthreads();
  const int c = t >> 1, h = t & 1;
  unsigned short* op = out + (size_t)c * 8192 + j0 + h * 32;
  #pragma unroll
  for (int q = 0; q < 4; ++q) {
    int rb = h * 32 + q * 8;
    uint4 w;
    w.x = (unsigned)f2bu(tile[rb + 0][c]) | ((unsigned)f2bu(tile[rb + 1][c]) << 16);
    w.y = (unsigned)f2bu(tile[rb + 2][c]) | ((unsigned)f2bu(tile[rb + 3][c]) << 16);
    w.z = (unsigned)f2bu(tile[rb + 4][c]) | ((unsigned)f2bu(tile[rb + 5][c]) << 16);
    w.w = (unsigned)f2bu(tile[rb + 6][c]) | ((unsigned)f2bu(tile[rb + 7][c]) << 16);
    *(uint4*)(op + q * 8) = w;
  }
}

// -------- K3/K5: C[8192x128] = A(f32,cvt bf16) @ B^T(bf16 [128][8192]) --------
// EPI 0: AX epilogue -> z_l (f32 ws), s_l (softmax, f32 d_out)
// EPI 1: plain write of acc -> As (f32 ws)
template<int EPI>
__global__ __launch_bounds__(512)
void k_gemm(const float* __restrict__ Ag, const unsigned short* __restrict__ Bt,
            const float* __restrict__ dinv, const float* __restrict__ Xg,
            const float* __restrict__ We, const float* __restrict__ be,
            const float* __restrict__ Wa, const float* __restrict__ ba,
            float* __restrict__ sl_out, float* __restrict__ zl_out,
            float* __restrict__ as_out) {
  __shared__ alignas(16) char smem[81920];   // A: 2x8KB, B: 2x32KB
  char* Ab = smem;
  char* Bb = smem + 16384;
  const int t = threadIdx.x;
  const int wv = t >> 6, ln = t & 63;
  const int i0 = blockIdx.x * 32;

  // staging coords
  const int s_ar = t >> 5;      // A row base (chunk i adds 16)
  const int s_as = t & 31;      // f32x4 slot in 128-wide row
  const int s_bn = t >> 4;      // B n-row base (chunk i adds 32)
  const int s_bk = t & 15;      // 16B slot in 256B row

  // fragment coords
  const int f_r = ln & 15;
  const int f_kb = (ln >> 4) << 4;    // byte offset of k-subgroup

  v4f acc[2] = {{0.f,0.f,0.f,0.f},{0.f,0.f,0.f,0.f}};
  float4 arg[2];
  uint4 brg[4];

  auto loadA = [&](int k0) {
    #pragma unroll
    for (int i = 0; i < 2; ++i) {
      int row = s_ar + i * 16;
      arg[i] = *(const float4*)(Ag + (size_t)(i0 + row) * 8192 + k0 + s_as * 4);
    }
  };
  auto loadB = [&](int k0) {
    #pragma unroll
    for (int i = 0; i < 4; ++i) {
      int n = s_bn + i * 32;
      brg[i] = *(const uint4*)(Bt + (size_t)n * 8192 + k0 + s_bk * 8);
    }
  };
  auto writeA = [&](int buf) {
    #pragma unroll
    for (int i = 0; i < 2; ++i) {
      int row = s_ar + i * 16;
      unsigned lo = (unsigned)f2bu(arg[i].x) | ((unsigned)f2bu(arg[i].y) << 16);
      unsigned hi = (unsigned)f2bu(arg[i].z) | ((unsigned)f2bu(arg[i].w) << 16);
      int off = ((row << 8) + s_as * 8) ^ ((row & 7) << 4);
      *(uint2*)(Ab + buf * 8192 + off) = make_uint2(lo, hi);
    }
  };
  auto writeB = [&](int buf) {
    #pragma unroll
    for (int i = 0; i < 4; ++i) {
      int n = s_bn + i * 32;
      int off = ((n << 8) + s_bk * 16) ^ ((n & 7) << 4);
      *(uint4*)(Bb + buf * 32768 + off) = brg[i];
    }
  };

  loadA(0); loadB(0);
  writeA(0); writeB(0);
  __syncthreads();

  const int nrow = (wv << 4) + f_r;
  int cur = 0;
  for (int kt = 0; kt < 64; ++kt) {
    if (kt < 63) { loadA((kt + 1) * 128); loadB((kt + 1) * 128); }
    #pragma unroll
    for (int ks = 0; ks < 4; ++ks) {
      int boff = ((nrow << 8) + ks * 64 + f_kb) ^ ((nrow & 7) << 4);
      v8s bf = *(const v8s*)(Bb + cur * 32768 + boff);
      #pragma unroll
      for (int mt = 0; mt < 2; ++mt) {
        int arow = mt * 16 + f_r;
        int aoff = ((arow << 8) + ks * 64 + f_kb) ^ ((f_r & 7) << 4);
        v8s af = *(const v8s*)(Ab + cur * 8192 + aoff);
        acc[mt] = __builtin_amdgcn_mfma_f32_16x16x32_bf16(af, bf, acc[mt], 0, 0, 0);
      }
    }
    if (kt < 63) { writeA(cur ^ 1); writeB(cur ^ 1); }
    __syncthreads();
    cur ^= 1;
  }

  const int col = (wv << 4) + f_r;
  if constexpr (EPI == 0) {
    // E1: AX = dinv_i*(acc + dinv_i*X) -> bf16 LDS [32][128] swizzled (in Ab)
    #pragma unroll
    for (int mt = 0; mt < 2; ++mt) {
      #pragma unroll
      for (int r = 0; r < 4; ++r) {
        int row = mt * 16 + ((ln >> 4) << 2) + r;
        int gi = i0 + row;
        float di = dinv[gi];
        float ax = di * (acc[mt][r] + di * Xg[(size_t)gi * 128 + col]);
        int off = ((row << 8) + col * 2) ^ ((row & 7) << 4);
        *(unsigned short*)(Ab + off) = f2bu(ax);
      }
    }
    __syncthreads();
    // E2: z = AX@We^T, logits = AX@Wa^T via MFMA (W loaded f32->bf16 from L2)
    v4f zac[2] = {{0.f,0.f,0.f,0.f},{0.f,0.f,0.f,0.f}};
    v4f lac[2] = {{0.f,0.f,0.f,0.f},{0.f,0.f,0.f,0.f}};
    const int kk = (ln >> 4) << 3;
    #pragma unroll
    for (int ks = 0; ks < 4; ++ks) {
      int k = ks * 32 + kk;
      float4 w0 = *(const float4*)(We + col * 128 + k);
      float4 w1 = *(const float4*)(We + col * 128 + k + 4);
      v8s bfe = pack8(w0, w1);
      float4 u0 = *(const float4*)(Wa + col * 128 + k);
      float4 u1 = *(const float4*)(Wa + col * 128 + k + 4);
      v8s bfa = pack8(u0, u1);
      #pragma unroll
      for (int mt = 0; mt < 2; ++mt) {
        int arow = mt * 16 + f_r;
        int aoff = ((arow << 8) + k * 2) ^ ((f_r & 7) << 4);
        v8s af = *(const v8s*)(Ab + aoff);
        zac[mt] = __builtin_amdgcn_mfma_f32_16x16x32_bf16(af, bfe, zac[mt], 0, 0, 0);
        lac[mt] = __builtin_amdgcn_mfma_f32_16x16x32_bf16(af, bfa, lac[mt], 0, 0, 0);
      }
    }
    float bev = be[col], bav = ba[col];
    float* lg = (float*)Bb;     // [32][128] f32 logits
    #pragma unroll
    for (int mt = 0; mt < 2; ++mt) {
      #pragma unroll
      for (int r = 0; r < 4; ++r) {
        int row = mt * 16 + ((ln >> 4) << 2) + r;
        zl_out[(size_t)(i0 + row) * 128 + col] = zac[mt][r] + bev;
        lg[row * 128 + col] = lac[mt][r] + bav;
      }
    }
    __syncthreads();
    // E5: row softmax (16 threads per row)
    const int srow = t >> 4, sg = t & 15;
    const float* lr = lg + srow * 128 + sg * 8;
    float4 v0 = *(const float4*)(lr);
    float4 v1 = *(const float4*)(lr + 4);
    float mx = fmaxf(fmaxf(fmaxf(v0.x, v0.y), fmaxf(v0.z, v0.w)),
                     fmaxf(fmaxf(v1.x, v1.y), fmaxf(v1.z, v1.w)));
    #pragma unroll
    for (int d = 1; d < 16; d <<= 1) mx = fmaxf(mx, __shfl_xor(mx, d));
    float e0 = __expf(v0.x - mx), e1 = __expf(v0.y - mx);
    float e2 = __expf(v0.z - mx), e3 = __expf(v0.w - mx);
    float e4 = __expf(v1.x - mx), e5 = __expf(v1.y - mx);
    float e6 = __expf(v1.z - mx), e7 = __expf(v1.w - mx);
    float sum = ((e0 + e1) + (e2 + e3)) + ((e4 + e5) + (e6 + e7));
    #pragma unroll
    for (int d = 1; d < 16; d <<= 1) sum += __shfl_xor(sum, d);
    float inv = 1.0f / sum;
    float4 o0 = make_float4(e0 * inv, e1 * inv, e2 * inv, e3 * inv);
    float4 o1 = make_float4(e4 * inv, e5 * inv, e6 * inv, e7 * inv);
    float* op = sl_out + (size_t)(i0 + srow) * 128 + sg * 8;
    *(float4*)(op) = o0;
    *(float4*)(op + 4) = o1;
  } else {
    #pragma unroll
    for (int mt = 0; mt < 2; ++mt) {
      #pragma unroll
      for (int r = 0; r < 4; ++r) {
        int row = mt * 16 + ((ln >> 4) << 2) + r;
        as_out[(size_t)(i0 + row) * 128 + col] = acc[mt][r];
      }
    }
  }
}

// -------- K6: split-K outer products: X_next = s^T z, A_next = s^T (A s) --------
__global__ __launch_bounds__(256)
void k_outer(const unsigned short* __restrict__ slt, const unsigned short* __restrict__ zlt,
             const unsigned short* __restrict__ ast, float* __restrict__ parts) {
  const int t = threadIdx.x, wv = t >> 6, ln = t & 63;
  const int k0 = blockIdx.x * 128;
  const int lm = ln & 15, lk = (ln >> 4) << 3;
  v4f c1[2][8];
  v4f c2[2][8];
  #pragma unroll
  for (int mt = 0; mt < 2; ++mt)
    #pragma unroll
    for (int nt = 0; nt < 8; ++nt) { c1[mt][nt] = (v4f){0.f,0.f,0.f,0.f}; c2[mt][nt] = (v4f){0.f,0.f,0.f,0.f}; }
  #pragma unroll
  for (int ks = 0; ks < 4; ++ks) {
    int k = k0 + ks * 32 + lk;
    v8s a0 = *(const v8s*)(slt + (size_t)(wv * 32 + lm) * 8192 + k);
    v8s a1 = *(const v8s*)(slt + (size_t)(wv * 32 + 16 + lm) * 8192 + k);
    #pragma unroll
    for (int nt = 0; nt < 8; ++nt) {
      v8s bz = *(const v8s*)(zlt + (size_t)(nt * 16 + lm) * 8192 + k);
      v8s bs = *(const v8s*)(ast + (size_t)(nt * 16 + lm) * 8192 + k);
      c1[0][nt] = __builtin_amdgcn_mfma_f32_16x16x32_bf16(a0, bz, c1[0][nt], 0, 0, 0);
      c1[1][nt] = __builtin_amdgcn_mfma_f32_16x16x32_bf16(a1, bz, c1[1][nt], 0, 0, 0);
      c2[0][nt] = __builtin_amdgcn_mfma_f32_16x16x32_bf16(a0, bs, c2[0][nt], 0, 0, 0);
      c2[1][nt] = __builtin_amdgcn_mfma_f32_16x16x32_bf16(a1, bs, c2[1][nt], 0, 0, 0);
    }
  }
  float* p = parts + (size_t)blockIdx.x * 32768;
  #pragma unroll
  for (int mt = 0; mt < 2; ++mt)
    #pragma unroll
    for (int nt = 0; nt < 8; ++nt)
      #pragma unroll
      for (int r = 0; r < 4; ++r) {
        int m = wv * 32 + mt * 16 + ((ln >> 4) << 2) + r;
        int n = nt * 16 + lm;
        p[m * 128 + n] = c1[mt][nt][r];
        p[16384 + m * 128 + n] = c2[mt][nt][r];
      }
}

// -------- K7: reduce split-K partials -> X_next, A_next --------
__global__ __launch_bounds__(256)
void k_reduce(const float* __restrict__ parts, float* __restrict__ out) {
  const int o = blockIdx.x * 256 + threadIdx.x;   // < 32768
  float s = 0.f;
  for (int b = 0; b < 64; ++b) s += parts[(size_t)b * 32768 + o];
  out[o] = s;
}

extern "C" void kernel_launch(void* const* d_in, const int* in_sizes, int n_in,
                              void* d_out, int out_size, void* d_ws, size_t ws_size,
                              hipStream_t stream) {
  (void)in_sizes; (void)n_in; (void)out_size; (void)ws_size;
  const float* X  = (const float*)d_in[0];
  const float* A  = (const float*)d_in[1];
  const float* We = (const float*)d_in[2];
  const float* be = (const float*)d_in[3];
  const float* Wa = (const float*)d_in[4];
  const float* ba = (const float*)d_in[5];
  float* out = (float*)d_out;
  float* sl = out + 32768;            // s_l region of d_out

  char* ws = (char*)d_ws;
  float*          dinv = (float*)(ws + 0);
  unsigned short* xpt  = (unsigned short*)(ws + 32768);
  unsigned short* slt  = (unsigned short*)(ws + 2129920);
  unsigned short* zlt  = (unsigned short*)(ws + 4227072);
  unsigned short* ast  = (unsigned short*)(ws + 6324224);
  float*          zlf  = (float*)(ws + 8421376);
  float*          asf  = (float*)(ws + 12615680);
  float*          part = (float*)(ws + 16809984);

  k_deg<<<8192, 256, 0, stream>>>(A, dinv);
  k_transpose<true><<<128, 256, 0, stream>>>(X, xpt, dinv);
  k_gemm<0><<<256, 512, 0, stream>>>(A, xpt, dinv, X, We, be, Wa, ba, sl, zlf, nullptr);
  k_transpose<false><<<128, 256, 0, stream>>>(sl, slt, nullptr);
  k_transpose<false><<<128, 256, 0, stream>>>(zlf, zlt, nullptr);
  k_gemm<1><<<256, 512, 0, stream>>>(A, slt, nullptr, nullptr, nullptr, nullptr,
                                     nullptr, nullptr, nullptr, nullptr, asf);
  k_transpose<false><<<128, 256, 0, stream>>>(asf, ast, nullptr);
  k_outer<<<64, 256, 0, stream>>>(slt, zlt, ast, part);
  k_reduce<<<128, 256, 0, stream>>>(part, out);
}

// Round 2
// 280.585 us; speedup vs baseline: 1.4116x; 1.4116x over previous
//
#include <hip/hip_runtime.h>
#include <hip/hip_bf16.h>
#include <cstdint>

typedef short v8s __attribute__((ext_vector_type(8)));
typedef float v4f __attribute__((ext_vector_type(4)));

#define DEV __device__ __forceinline__

DEV unsigned short f2bu(float f) {
  unsigned u = __builtin_bit_cast(unsigned, f);
  u += 0x7fffu + ((u >> 16) & 1u);   // RNE to bf16
  return (unsigned short)(u >> 16);
}

DEV v8s pack8(const float4& a, const float4& b) {
  v8s r;
  r[0] = (short)f2bu(a.x); r[1] = (short)f2bu(a.y);
  r[2] = (short)f2bu(a.z); r[3] = (short)f2bu(a.w);
  r[4] = (short)f2bu(b.x); r[5] = (short)f2bu(b.y);
  r[6] = (short)f2bu(b.z); r[7] = (short)f2bu(b.w);
  return r;
}

// ---------------- K1: deg -> dinv = rsqrt(1 + rowsum(A)); optional A->bf16 ----------------
template<bool CVT>
__global__ __launch_bounds__(256)
void k_degcvt(const float* __restrict__ A, float* __restrict__ dinv,
              unsigned short* __restrict__ Abf) {
  const int row = blockIdx.x;
  const float* ar = A + (size_t)row * 8192;
  unsigned short* aw = Abf + (size_t)row * 8192;
  float s = 0.f;
  #pragma unroll
  for (int i = 0; i < 8; ++i) {
    const int c = i * 1024 + threadIdx.x * 4;
    float4 v = *(const float4*)(ar + c);
    s += (v.x + v.y) + (v.z + v.w);
    if constexpr (CVT) {
      uint2 w;
      w.x = (unsigned)f2bu(v.x) | ((unsigned)f2bu(v.y) << 16);
      w.y = (unsigned)f2bu(v.z) | ((unsigned)f2bu(v.w) << 16);
      *(uint2*)(aw + c) = w;
    }
  }
  #pragma unroll
  for (int d = 1; d < 64; d <<= 1) s += __shfl_xor(s, d);
  __shared__ float wsum[4];
  if ((threadIdx.x & 63) == 0) wsum[threadIdx.x >> 6] = s;
  __syncthreads();
  if (threadIdx.x == 0) {
    dinv[row] = rsqrtf(1.0f + ((wsum[0] + wsum[1]) + (wsum[2] + wsum[3])));
  }
}

// -------- K2: X [8192][128] f32 -> xpt [128][8192] bf16, row-scaled by dinv --------
template<bool SCALE>
__global__ __launch_bounds__(256)
void k_transpose(const float* __restrict__ in, unsigned short* __restrict__ out,
                 const float* __restrict__ dinv) {
  __shared__ float tile[64][129];
  const int j0 = blockIdx.x * 64;
  const int t = threadIdx.x;
  const int r0 = t >> 5, sl = t & 31;
  #pragma unroll
  for (int i = 0; i < 8; ++i) {
    int r = r0 + i * 8;
    float4 v = *(const float4*)(in + (size_t)(j0 + r) * 128 + sl * 4);
    float sc = 1.0f;
    if constexpr (SCALE) sc = dinv[j0 + r];
    tile[r][sl * 4 + 0] = v.x * sc;
    tile[r][sl * 4 + 1] = v.y * sc;
    tile[r][sl * 4 + 2] = v.z * sc;
    tile[r][sl * 4 + 3] = v.w * sc;
  }
  __syncthreads();
  const int c = t >> 1, h = t & 1;
  unsigned short* op = out + (size_t)c * 8192 + j0 + h * 32;
  #pragma unroll
  for (int q = 0; q < 4; ++q) {
    int rb = h * 32 + q * 8;
    uint4 w;
    w.x = (unsigned)f2bu(tile[rb + 0][c]) | ((unsigned)f2bu(tile[rb + 1][c]) << 16);
    w.y = (unsigned)f2bu(tile[rb + 2][c]) | ((unsigned)f2bu(tile[rb + 3][c]) << 16);
    w.z = (unsigned)f2bu(tile[rb + 4][c]) | ((unsigned)f2bu(tile[rb + 5][c]) << 16);
    w.w = (unsigned)f2bu(tile[rb + 6][c]) | ((unsigned)f2bu(tile[rb + 7][c]) << 16);
    *(uint4*)(op + q * 8) = w;
  }
}

// -------- K3/K5: LDS-free split-K GEMM: part[ks] = A[rows, kslice] @ B^T --------
// Block: 256 thr = 4 waves; wave owns 32 rows x 128 cols; grid (64, SPLITK).
// No LDS, no barriers: double-buffered register pipeline, direct global->reg.
#define LOADAB(BUF, K) do {                                                     \
    const int _k = (K);                                                         \
    _Pragma("unroll")                                                           \
    for (int mt = 0; mt < 2; ++mt) {                                            \
      if constexpr (ABF) {                                                      \
        ab[BUF][mt] = *(const v8s*)(Ab16 + rA[mt] + _k);                        \
      } else {                                                                  \
        af_[BUF][mt][0] = *(const float4*)(Af + rA[mt] + _k);                   \
        af_[BUF][mt][1] = *(const float4*)(Af + rA[mt] + _k + 4);               \
      }                                                                         \
    }                                                                           \
    _Pragma("unroll")                                                           \
    for (int nt = 0; nt < 8; ++nt)                                              \
      bb[BUF][nt] = *(const v8s*)(Bt + rB[nt] + _k);                            \
  } while (0)

#define MFMAS(BUF) do {                                                         \
    _Pragma("unroll")                                                           \
    for (int mt = 0; mt < 2; ++mt) {                                            \
      v8s a_;                                                                   \
      if constexpr (ABF) a_ = ab[BUF][mt];                                      \
      else a_ = pack8(af_[BUF][mt][0], af_[BUF][mt][1]);                        \
      _Pragma("unroll")                                                         \
      for (int nt = 0; nt < 8; ++nt)                                            \
        acc[mt][nt] = __builtin_amdgcn_mfma_f32_16x16x32_bf16(a_, bb[BUF][nt],  \
                                                              acc[mt][nt], 0, 0, 0); \
    }                                                                           \
  } while (0)

template<bool ABF, int SPLITK>
__global__ __launch_bounds__(256)
void k_gemm(const float* __restrict__ Af, const unsigned short* __restrict__ Ab16,
            const unsigned short* __restrict__ Bt, float* __restrict__ parts) {
  constexpr int KSTEPS = (8192 / SPLITK) / 32;
  const int t = threadIdx.x;
  const int wv = t >> 6, l = t & 63;
  const int i0 = blockIdx.x * 128 + wv * 32;
  const int k0 = blockIdx.y * (8192 / SPLITK);
  const int lr = l & 15;
  const int lk = (l >> 4) * 8;

  const size_t rA[2] = { (size_t)(i0 + lr) * 8192, (size_t)(i0 + 16 + lr) * 8192 };
  size_t rB[8];
  #pragma unroll
  for (int nt = 0; nt < 8; ++nt) rB[nt] = (size_t)(nt * 16 + lr) * 8192;

  v4f acc[2][8];
  #pragma unroll
  for (int mt = 0; mt < 2; ++mt)
    #pragma unroll
    for (int nt = 0; nt < 8; ++nt) acc[mt][nt] = (v4f){0.f, 0.f, 0.f, 0.f};

  v8s ab[2][2];
  float4 af_[2][2][2];
  v8s bb[2][8];

  LOADAB(0, k0 + lk);
  for (int kt = 0; kt < KSTEPS; kt += 2) {
    LOADAB(1, k0 + (kt + 1) * 32 + lk);
    MFMAS(0);
    if (kt + 2 < KSTEPS) LOADAB(0, k0 + (kt + 2) * 32 + lk);
    MFMAS(1);
  }

  float* p = parts + (size_t)blockIdx.y * (8192 * 128);
  #pragma unroll
  for (int mt = 0; mt < 2; ++mt)
    #pragma unroll
    for (int nt = 0; nt < 8; ++nt)
      #pragma unroll
      for (int r = 0; r < 4; ++r)
        p[(size_t)(i0 + mt * 16 + (l >> 4) * 4 + r) * 128 + nt * 16 + lr] = acc[mt][nt][r];
}

// -------- K4: reduce GEMM1 partials + epilogue + z/logit MFMA + softmax + T-writes --------
__global__ __launch_bounds__(256)
void k_post1(const float* __restrict__ parts, int nsplit,
             const float* __restrict__ dinv, const float* __restrict__ Xg,
             const float* __restrict__ We, const float* __restrict__ be,
             const float* __restrict__ Wa, const float* __restrict__ ba,
             float* __restrict__ sl_out, unsigned short* __restrict__ slt,
             unsigned short* __restrict__ zlt) {
  __shared__ alignas(16) unsigned short axs[32 * 128];   // swizzled bf16 AX
  __shared__ float lg[32 * 128];                          // logits f32
  __shared__ unsigned short sbf[32 * 130];
  __shared__ unsigned short zbf[32 * 130];
  const int t = threadIdx.x;
  const int i0 = blockIdx.x * 32;

  { // Phase A: sum partials, epilogue AX = di*(acc + di*X), bf16 -> swizzled LDS
    const int r = t >> 3, cg = t & 7;
    const size_t base = (size_t)(i0 + r) * 128 + cg * 16;
    float acc[16];
    #pragma unroll
    for (int q = 0; q < 4; ++q) {
      float4 v = *(const float4*)(parts + base + q * 4);
      acc[q * 4 + 0] = v.x; acc[q * 4 + 1] = v.y;
      acc[q * 4 + 2] = v.z; acc[q * 4 + 3] = v.w;
    }
    for (int s = 1; s < nsplit; ++s) {
      #pragma unroll
      for (int q = 0; q < 4; ++q) {
        float4 v = *(const float4*)(parts + (size_t)s * 1048576 + base + q * 4);
        acc[q * 4 + 0] += v.x; acc[q * 4 + 1] += v.y;
        acc[q * 4 + 2] += v.z; acc[q * 4 + 3] += v.w;
      }
    }
    const float di = dinv[i0 + r];
    unsigned short bx[16];
    #pragma unroll
    for (int q = 0; q < 4; ++q) {
      float4 xv = *(const float4*)(Xg + base + q * 4);
      bx[q * 4 + 0] = f2bu(di * (acc[q * 4 + 0] + di * xv.x));
      bx[q * 4 + 1] = f2bu(di * (acc[q * 4 + 1] + di * xv.y));
      bx[q * 4 + 2] = f2bu(di * (acc[q * 4 + 2] + di * xv.z));
      bx[q * 4 + 3] = f2bu(di * (acc[q * 4 + 3] + di * xv.w));
    }
    char* Ab = (char*)axs;
    const int b0 = (r << 8) + cg * 32, sw = (r & 7) << 4;
    uint4 w0, w1;
    w0.x = (unsigned)bx[0] | ((unsigned)bx[1] << 16);
    w0.y = (unsigned)bx[2] | ((unsigned)bx[3] << 16);
    w0.z = (unsigned)bx[4] | ((unsigned)bx[5] << 16);
    w0.w = (unsigned)bx[6] | ((unsigned)bx[7] << 16);
    w1.x = (unsigned)bx[8] | ((unsigned)bx[9] << 16);
    w1.y = (unsigned)bx[10] | ((unsigned)bx[11] << 16);
    w1.z = (unsigned)bx[12] | ((unsigned)bx[13] << 16);
    w1.w = (unsigned)bx[14] | ((unsigned)bx[15] << 16);
    *(uint4*)(Ab + (b0 ^ sw)) = w0;
    *(uint4*)(Ab + ((b0 + 16) ^ sw)) = w1;
  }
  __syncthreads();

  const int wv = t >> 6, l = t & 63, fr = l & 15;
  { // Phase B+C: z = AX@We^T + be, logits = AX@Wa^T + ba (MFMA), store to LDS
    v4f zac[2][2], lac[2][2];
    #pragma unroll
    for (int a = 0; a < 2; ++a)
      #pragma unroll
      for (int b = 0; b < 2; ++b) {
        zac[a][b] = (v4f){0.f, 0.f, 0.f, 0.f};
        lac[a][b] = (v4f){0.f, 0.f, 0.f, 0.f};
      }
    const int kk = (l >> 4) * 8;
    #pragma unroll
    for (int ks = 0; ks < 4; ++ks) {
      const int k = ks * 32 + kk;
      #pragma unroll
      for (int nj = 0; nj < 2; ++nj) {
        const int col = nj * 64 + wv * 16 + fr;
        v8s bfe = pack8(*(const float4*)(We + col * 128 + k),
                        *(const float4*)(We + col * 128 + k + 4));
        v8s bfa = pack8(*(const float4*)(Wa + col * 128 + k),
                        *(const float4*)(Wa + col * 128 + k + 4));
        #pragma unroll
        for (int mt = 0; mt < 2; ++mt) {
          const int arow = mt * 16 + fr;
          v8s af = *(const v8s*)((char*)axs + (((arow << 8) + k * 2) ^ ((fr & 7) << 4)));
          zac[mt][nj] = __builtin_amdgcn_mfma_f32_16x16x32_bf16(af, bfe, zac[mt][nj], 0, 0, 0);
          lac[mt][nj] = __builtin_amdgcn_mfma_f32_16x16x32_bf16(af, bfa, lac[mt][nj], 0, 0, 0);
        }
      }
    }
    #pragma unroll
    for (int mt = 0; mt < 2; ++mt)
      #pragma unroll
      for (int nj = 0; nj < 2; ++nj)
        #pragma unroll
        for (int r4 = 0; r4 < 4; ++r4) {
          const int row = mt * 16 + (l >> 4) * 4 + r4;
          const int col = nj * 64 + wv * 16 + fr;
          lg[row * 128 + col] = lac[mt][nj][r4] + ba[col];
          zbf[row * 130 + col] = f2bu(zac[mt][nj][r4] + be[col]);
        }
  }
  __syncthreads();

  { // Phase D: softmax, 8 threads per row
    const int r = t >> 3, g = t & 7;
    const float* lp = lg + r * 128 + g * 16;
    float x[16];
    #pragma unroll
    for (int q = 0; q < 4; ++q) {
      float4 v = *(const float4*)(lp + q * 4);
      x[q * 4 + 0] = v.x; x[q * 4 + 1] = v.y; x[q * 4 + 2] = v.z; x[q * 4 + 3] = v.w;
    }
    float mx = x[0];
    #pragma unroll
    for (int j = 1; j < 16; ++j) mx = fmaxf(mx, x[j]);
    #pragma unroll
    for (int d = 1; d < 8; d <<= 1) mx = fmaxf(mx, __shfl_xor(mx, d));
    float sum = 0.f;
    #pragma unroll
    for (int j = 0; j < 16; ++j) { x[j] = __expf(x[j] - mx); sum += x[j]; }
    #pragma unroll
    for (int d = 1; d < 8; d <<= 1) sum += __shfl_xor(sum, d);
    const float inv = 1.0f / sum;
    float* op = sl_out + (size_t)(i0 + r) * 128 + g * 16;
    #pragma unroll
    for (int q = 0; q < 4; ++q) {
      float4 o;
      o.x = x[q * 4 + 0] * inv; o.y = x[q * 4 + 1] * inv;
      o.z = x[q * 4 + 2] * inv; o.w = x[q * 4 + 3] * inv;
      *(float4*)(op + q * 4) = o;
    }
    #pragma unroll
    for (int j = 0; j < 16; ++j) sbf[r * 130 + g * 16 + j] = f2bu(x[j] * inv);
  }
  __syncthreads();

  { // Phase E: transposed bf16 writes (t<128: s_l -> slt; t>=128: z_l -> zlt)
    const int c = t & 127;
    const unsigned short* src = (t < 128) ? sbf : zbf;
    unsigned short* dst = (t < 128) ? slt : zlt;
    unsigned short* o = dst + (size_t)c * 8192 + i0;
    #pragma unroll
    for (int q = 0; q < 4; ++q) {
      uint4 w;
      w.x = (unsigned)src[(q * 8 + 0) * 130 + c] | ((unsigned)src[(q * 8 + 1) * 130 + c] << 16);
      w.y = (unsigned)src[(q * 8 + 2) * 130 + c] | ((unsigned)src[(q * 8 + 3) * 130 + c] << 16);
      w.z = (unsigned)src[(q * 8 + 4) * 130 + c] | ((unsigned)src[(q * 8 + 5) * 130 + c] << 16);
      w.w = (unsigned)src[(q * 8 + 6) * 130 + c] | ((unsigned)src[(q * 8 + 7) * 130 + c] << 16);
      *(uint4*)(o + q * 8) = w;
    }
  }
}

// -------- K6: reduce GEMM2 partials -> bf16 transposed ast [128][8192] --------
__global__ __launch_bounds__(256)
void k_post2(const float* __restrict__ parts, int nsplit, unsigned short* __restrict__ ast) {
  __shared__ unsigned short sb[32 * 130];
  const int t = threadIdx.x;
  const int i0 = blockIdx.x * 32;
  {
    const int r = t >> 3, cg = t & 7;
    const size_t base = (size_t)(i0 + r) * 128 + cg * 16;
    float acc[16];
    #pragma unroll
    for (int q = 0; q < 4; ++q) {
      float4 v = *(const float4*)(parts + base + q * 4);
      acc[q * 4 + 0] = v.x; acc[q * 4 + 1] = v.y;
      acc[q * 4 + 2] = v.z; acc[q * 4 + 3] = v.w;
    }
    for (int s = 1; s < nsplit; ++s) {
      #pragma unroll
      for (int q = 0; q < 4; ++q) {
        float4 v = *(const float4*)(parts + (size_t)s * 1048576 + base + q * 4);
        acc[q * 4 + 0] += v.x; acc[q * 4 + 1] += v.y;
        acc[q * 4 + 2] += v.z; acc[q * 4 + 3] += v.w;
      }
    }
    #pragma unroll
    for (int j = 0; j < 16; ++j) sb[r * 130 + cg * 16 + j] = f2bu(acc[j]);
  }
  __syncthreads();
  if (t < 128) {
    unsigned short* o = ast + (size_t)t * 8192 + i0;
    #pragma unroll
    for (int q = 0; q < 4; ++q) {
      uint4 w;
      w.x = (unsigned)sb[(q * 8 + 0) * 130 + t] | ((unsigned)sb[(q * 8 + 1) * 130 + t] << 16);
      w.y = (unsigned)sb[(q * 8 + 2) * 130 + t] | ((unsigned)sb[(q * 8 + 3) * 130 + t] << 16);
      w.z = (unsigned)sb[(q * 8 + 4) * 130 + t] | ((unsigned)sb[(q * 8 + 5) * 130 + t] << 16);
      w.w = (unsigned)sb[(q * 8 + 6) * 130 + t] | ((unsigned)sb[(q * 8 + 7) * 130 + t] << 16);
      *(uint4*)(o + q * 8) = w;
    }
  }
}

// -------- K7: split-K outer products: X_next = s^T z, A_next = s^T (A s) --------
__global__ __launch_bounds__(256)
void k_outer(const unsigned short* __restrict__ slt, const unsigned short* __restrict__ zlt,
             const unsigned short* __restrict__ ast, float* __restrict__ parts) {
  const int t = threadIdx.x, wv = t >> 6, ln = t & 63;
  const int k0 = blockIdx.x * 128;
  const int lm = ln & 15, lk = (ln >> 4) << 3;
  v4f c1[2][8];
  v4f c2[2][8];
  #pragma unroll
  for (int mt = 0; mt < 2; ++mt)
    #pragma unroll
    for (int nt = 0; nt < 8; ++nt) { c1[mt][nt] = (v4f){0.f,0.f,0.f,0.f}; c2[mt][nt] = (v4f){0.f,0.f,0.f,0.f}; }
  #pragma unroll
  for (int ks = 0; ks < 4; ++ks) {
    int k = k0 + ks * 32 + lk;
    v8s a0 = *(const v8s*)(slt + (size_t)(wv * 32 + lm) * 8192 + k);
    v8s a1 = *(const v8s*)(slt + (size_t)(wv * 32 + 16 + lm) * 8192 + k);
    #pragma unroll
    for (int nt = 0; nt < 8; ++nt) {
      v8s bz = *(const v8s*)(zlt + (size_t)(nt * 16 + lm) * 8192 + k);
      v8s bs = *(const v8s*)(ast + (size_t)(nt * 16 + lm) * 8192 + k);
      c1[0][nt] = __builtin_amdgcn_mfma_f32_16x16x32_bf16(a0, bz, c1[0][nt], 0, 0, 0);
      c1[1][nt] = __builtin_amdgcn_mfma_f32_16x16x32_bf16(a1, bz, c1[1][nt], 0, 0, 0);
      c2[0][nt] = __builtin_amdgcn_mfma_f32_16x16x32_bf16(a0, bs, c2[0][nt], 0, 0, 0);
      c2[1][nt] = __builtin_amdgcn_mfma_f32_16x16x32_bf16(a1, bs, c2[1][nt], 0, 0, 0);
    }
  }
  float* p = parts + (size_t)blockIdx.x * 32768;
  #pragma unroll
  for (int mt = 0; mt < 2; ++mt)
    #pragma unroll
    for (int nt = 0; nt < 8; ++nt)
      #pragma unroll
      for (int r = 0; r < 4; ++r) {
        int m = wv * 32 + mt * 16 + ((ln >> 4) << 2) + r;
        int n = nt * 16 + lm;
        p[m * 128 + n] = c1[mt][nt][r];
        p[16384 + m * 128 + n] = c2[mt][nt][r];
      }
}

// -------- K8: reduce outer partials -> X_next, A_next --------
__global__ __launch_bounds__(256)
void k_reduce(const float* __restrict__ parts, float* __restrict__ out) {
  const int o = blockIdx.x * 256 + threadIdx.x;   // < 32768
  float s = 0.f;
  for (int b = 0; b < 64; ++b) s += parts[(size_t)b * 32768 + o];
  out[o] = s;
}

extern "C" void kernel_launch(void* const* d_in, const int* in_sizes, int n_in,
                              void* d_out, int out_size, void* d_ws, size_t ws_size,
                              hipStream_t stream) {
  (void)in_sizes; (void)n_in; (void)out_size;
  const float* X  = (const float*)d_in[0];
  const float* A  = (const float*)d_in[1];
  const float* We = (const float*)d_in[2];
  const float* be = (const float*)d_in[3];
  const float* Wa = (const float*)d_in[4];
  const float* ba = (const float*)d_in[5];
  float* out = (float*)d_out;
  float* sl = out + 32768;            // s_l region of d_out

  char* ws = (char*)d_ws;
  constexpr size_t OFF_XPT  = 32768;
  constexpr size_t OFF_SLT  = OFF_XPT + 2097152;   // 2129920
  constexpr size_t OFF_ZLT  = OFF_SLT + 2097152;   // 4227072
  constexpr size_t OFF_AST  = OFF_ZLT + 2097152;   // 6324224
  constexpr size_t OFF_PART = OFF_AST + 2097152;   // 8421376 (GEMM partials; k_outer reuses)
  constexpr size_t OFF_ABF  = OFF_PART + 33554432; // 41975808
  constexpr size_t NEED_SK8 = OFF_ABF;
  constexpr size_t NEED_ABF = OFF_ABF + 134217728ull;

  float*          dinv = (float*)(ws + 0);
  unsigned short* xpt  = (unsigned short*)(ws + OFF_XPT);
  unsigned short* slt  = (unsigned short*)(ws + OFF_SLT);
  unsigned short* zlt  = (unsigned short*)(ws + OFF_ZLT);
  unsigned short* ast  = (unsigned short*)(ws + OFF_AST);
  float*          part = (float*)(ws + OFF_PART);
  unsigned short* abfp = (unsigned short*)(ws + OFF_ABF);

  const bool abf = ws_size >= NEED_ABF;
  const int  sk  = (abf || ws_size >= NEED_SK8) ? 8 : 4;

  if (abf) k_degcvt<true><<<8192, 256, 0, stream>>>(A, dinv, abfp);
  else     k_degcvt<false><<<8192, 256, 0, stream>>>(A, dinv, abfp);

  k_transpose<true><<<128, 256, 0, stream>>>(X, xpt, dinv);

  if (abf)          k_gemm<true, 8><<<dim3(64, 8), 256, 0, stream>>>(A, abfp, xpt, part);
  else if (sk == 8) k_gemm<false, 8><<<dim3(64, 8), 256, 0, stream>>>(A, abfp, xpt, part);
  else              k_gemm<false, 4><<<dim3(64, 4), 256, 0, stream>>>(A, abfp, xpt, part);

  k_post1<<<256, 256, 0, stream>>>(part, sk, dinv, X, We, be, Wa, ba, sl, slt, zlt);

  if (abf)          k_gemm<true, 8><<<dim3(64, 8), 256, 0, stream>>>(A, abfp, slt, part);
  else if (sk == 8) k_gemm<false, 8><<<dim3(64, 8), 256, 0, stream>>>(A, abfp, slt, part);
  else              k_gemm<false, 4><<<dim3(64, 4), 256, 0, stream>>>(A, abfp, slt, part);

  k_post2<<<256, 256, 0, stream>>>(part, sk, ast);
  k_outer<<<64, 256, 0, stream>>>(slt, zlt, ast, part);
  k_reduce<<<128, 256, 0, stream>>>(part, out);
}